// Round 18
// baseline (71.207 us; speedup 1.0000x reference)
//
#include <hip/hip_runtime.h>

#define NN   2048
#define EE   65536
#define EDIM 64
#define LL   5
#define NP   ((size_t)NN * NN)
#define TG   524288              // total threads in pairs kernel (1024 x 512)
#define QS   0.375f
#define QINV 2.6666667f

__device__ __forceinline__ void gload_lds16(const void* g, void* l) {
  __builtin_amdgcn_global_load_lds(
      (const __attribute__((address_space(1))) void*)g,
      (__attribute__((address_space(3))) void*)l, 16, 0, 0);
}

// Kernel 1: dotsQ[l][e] = int8 round((attr[e]·ev[l]) / 0.375), planes of 64 KB.
__global__ __launch_bounds__(256) void dots_kernel(
    const float* __restrict__ edge_attr,
    const float* __restrict__ edge_vector,
    signed char* __restrict__ dotsQ) {
  const int lane = threadIdx.x & 63;
  const int wib  = threadIdx.x >> 6;
  const int dg   = lane & 15;
  const int es   = lane >> 4;
  const int e    = blockIdx.x * 16 + wib * 4 + es;

  const float4 a = *(const float4*)(edge_attr + e * EDIM + dg * 4);
  float d[LL];
#pragma unroll
  for (int l = 0; l < LL; ++l) {
    const float4 ev = *(const float4*)(edge_vector + l * EDIM + dg * 4);
    d[l] = a.x * ev.x + a.y * ev.y + a.z * ev.z + a.w * ev.w;
  }
#pragma unroll
  for (int s = 1; s <= 8; s <<= 1) {
#pragma unroll
    for (int l = 0; l < LL; ++l) d[l] += __shfl_xor(d[l], s, 64);
  }
  if (dg < LL) {
    const float dv = (dg == 0) ? d[0] : (dg == 1) ? d[1] : (dg == 2) ? d[2]
                   : (dg == 3) ? d[3] : d[4];
    const float qf = fminf(fmaxf(dv * QINV, -127.f), 127.f);
    dotsQ[dg * EE + e] = (signed char)__float2int_rn(qf);
  }
}

// ---------- PROBE 1: index read + pack only ----------
__global__ __launch_bounds__(512) void idx_probe(
    const int* __restrict__ ept, float* __restrict__ scrap) {
  const int tid = blockIdx.x * 512 + threadIdx.x;
  unsigned pk[20];
  unsigned cp = 0u;
#pragma unroll
  for (int g = 0; g < 2; ++g) {
    const size_t gid = (size_t)g * TG + (size_t)tid;
    const int4* p = (const int4*)(ept + gid * 20);
#pragma unroll
    for (int q = 0; q < 5; ++q) {
      const int4 v = p[q];
#pragma unroll
      for (int jj = 0; jj < 4; ++jj) {
        const int sl = q * 4 + jj;
        const int k  = g * 4 + sl / 5;
        const int id = (jj == 0) ? v.x : (jj == 1) ? v.y : (jj == 2) ? v.z : v.w;
        cp += ((id >= 0) ? 1u : 0u) << (k * 4);
        const unsigned e16 = (id < 0) ? 0u : (unsigned)id;
        const int sg = g * 20 + sl;
        if ((sg & 1) == 0) pk[sg >> 1] = e16;
        else               pk[sg >> 1] |= (e16 << 16);
      }
    }
  }
  unsigned x = cp;
#pragma unroll
  for (int i = 0; i < 20; ++i) x ^= pk[i];
  scrap[tid] = (float)x;
}

// ---------- PROBE 2: staging only (exact 5-plane loop + barriers/drains) ----------
__global__ __launch_bounds__(512) void stage_probe(
    const signed char* __restrict__ dotsQ, float* __restrict__ scrap) {
  __shared__ __align__(16) signed char tab[EE];
  const int ltid = threadIdx.x;
  const int tid  = blockIdx.x * 512 + ltid;
  int s = 0;
#pragma unroll
  for (int l = 0; l < LL; ++l) {
    if (l) __syncthreads();
    const signed char* src = dotsQ + (size_t)l * EE;
#pragma unroll
    for (int r = 0; r < 8; ++r) {
      const int c = (r * 512 + ltid) * 16;
      gload_lds16(src + c, tab + c);
    }
    __syncthreads();                       // vmcnt drain + visibility
    s += (int)tab[(ltid * 67) & 0xFFFF];   // touch, prevent elision
  }
  scrap[tid] = (float)s;
}

// ---------- PROBE 3: gathers only (stage once; same DS ops + barriers) ----------
__global__ __launch_bounds__(512) void gather_probe(
    const signed char* __restrict__ dotsQ, float* __restrict__ scrap) {
  __shared__ __align__(16) signed char tab[EE];
  const int ltid = threadIdx.x;
  const int tid  = blockIdx.x * 512 + ltid;
  const signed char* src = dotsQ;
#pragma unroll
  for (int r = 0; r < 8; ++r) {
    const int c = (r * 512 + ltid) * 16;
    gload_lds16(src + c, tab + c);
  }
  __syncthreads();
  int s = 0;
  unsigned h = (unsigned)tid * 2654435761u + 12345u;
#pragma unroll
  for (int l = 0; l < LL; ++l) {
#pragma unroll
    for (int k = 0; k < 8; ++k) {
      h = h * 1664525u + 1013904223u;      // LCG: random table addrs
      s += (int)tab[h >> 16];
    }
    __syncthreads();                        // match real per-pass barriers
    __syncthreads();
  }
  scrap[tid] = (float)s;
}

// ---------- REAL kernel: R14-exact (best known, 39.3 us total) ----------
__global__ __launch_bounds__(512) void pairs_kernel(
    const int* __restrict__ ept,
    const signed char* __restrict__ dotsQ,
    float* __restrict__ out) {
  __shared__ __align__(16) signed char tab[EE];
  const int ltid = threadIdx.x;
  const int tid  = blockIdx.x * 512 + ltid;

  unsigned pk[20];
  unsigned cp = 0u;
#pragma unroll
  for (int g = 0; g < 2; ++g) {
    const size_t gid = (size_t)g * TG + (size_t)tid;
    const int4* p = (const int4*)(ept + gid * 20);
#pragma unroll
    for (int q = 0; q < 5; ++q) {
      const int4 v = p[q];
#pragma unroll
      for (int jj = 0; jj < 4; ++jj) {
        const int sl = q * 4 + jj;
        const int k  = g * 4 + sl / 5;
        const int id = (jj == 0) ? v.x : (jj == 1) ? v.y : (jj == 2) ? v.z : v.w;
        cp += ((id >= 0) ? 1u : 0u) << (k * 4);
        const unsigned e16 = (id < 0) ? 0u : (unsigned)id;
        const int sg = g * 20 + sl;
        if ((sg & 1) == 0) pk[sg >> 1] = e16;
        else               pk[sg >> 1] |= (e16 << 16);
      }
    }
  }
  asm volatile("" : "+v"(pk[0]), "+v"(pk[1]), "+v"(pk[2]), "+v"(pk[3]),
                    "+v"(pk[4]), "+v"(pk[5]), "+v"(pk[6]), "+v"(pk[7]),
                    "+v"(pk[8]), "+v"(pk[9]), "+v"(pk[10]), "+v"(pk[11]),
                    "+v"(pk[12]), "+v"(pk[13]), "+v"(pk[14]), "+v"(pk[15]),
                    "+v"(pk[16]), "+v"(pk[17]), "+v"(pk[18]), "+v"(pk[19]),
                    "+v"(cp));

  int sum[8];
#pragma unroll
  for (int k = 0; k < 8; ++k) sum[k] = 0;
  int t0v[LL];

#pragma unroll
  for (int l = 0; l < LL; ++l) {
    if (l) __syncthreads();
    const signed char* src = dotsQ + (size_t)l * EE;
#pragma unroll
    for (int r = 0; r < 8; ++r) {
      const int c = (r * 512 + ltid) * 16;
      gload_lds16(src + c, tab + c);
    }
    __syncthreads();
    t0v[l] = (int)tab[0];
#pragma unroll
    for (int k = 0; k < 8; ++k) {
      const int sg = k * LL + l;
      const unsigned r = pk[sg >> 1];
      const unsigned id = (sg & 1) ? (r >> 16) : (r & 0xffffu);
      sum[k] += (int)tab[id];
    }
  }

  const int S4 = t0v[4];
  const int S3 = S4 + t0v[3];
  const int S2 = S3 + t0v[2];
  const int S1 = S2 + t0v[1];
  const int S0 = S1 + t0v[0];

#pragma unroll
  for (int g = 0; g < 2; ++g) {
    const size_t gid = (size_t)g * TG + (size_t)tid;
    float rr[4];
#pragma unroll
    for (int j = 0; j < 4; ++j) {
      const int k = g * 4 + j;
      const unsigned cnt = (cp >> (k * 4)) & 15u;
      const int corr = (cnt == 5) ? 0
                     : (cnt == 4) ? S4
                     : (cnt == 3) ? S3
                     : (cnt == 2) ? S2
                     : (cnt == 1) ? S1 : S0;
      rr[j] = (QS * (float)(sum[k] - corr)) / ((float)cnt + 1e-10f);
    }
    ((float4*)out)[gid] = make_float4(rr[0], rr[1], rr[2], rr[3]);
  }
}

extern "C" void kernel_launch(void* const* d_in, const int* in_sizes, int n_in,
                              void* d_out, int out_size, void* d_ws, size_t ws_size,
                              hipStream_t stream) {
  const float* edge_attr   = (const float*)d_in[1];
  const float* edge_vector = (const float*)d_in[2];
  const int*   ept         = (const int*)d_in[3];
  float* out = (float*)d_out;
  signed char* dotsQ = (signed char*)d_ws;             // 320 KB
  float* scrap = (float*)((char*)d_ws + (4 << 20));    // probe scratch

  dots_kernel<<<EE / 16, 256, 0, stream>>>(edge_attr, edge_vector, dotsQ);

  // --- instrumentation probes (same grid/regime as real kernel) ---
  if (ws_size >= (4u << 20) + (size_t)TG * 4) {
    idx_probe<<<1024, 512, 0, stream>>>(ept, scrap);
    stage_probe<<<1024, 512, 0, stream>>>(dotsQ, scrap);
    gather_probe<<<1024, 512, 0, stream>>>(dotsQ, scrap);
  }

  // --- real output kernel (R14-exact) ---
  pairs_kernel<<<1024, 512, 0, stream>>>(ept, dotsQ, out);
}

// Round 19
// 39.844 us; speedup vs baseline: 1.7871x; 1.7871x over previous
//
#include <hip/hip_runtime.h>

#define NN   2048
#define EE   65536
#define EDIM 64
#define LL   5
#define TG   524288              // total threads in pairs kernel (512 x 1024)
#define QS   0.375f
#define QINV 2.6666667f

#define WAITV(n) asm volatile("s_waitcnt vmcnt(" #n ")" ::: "memory")
#define WAITL()  asm volatile("s_waitcnt lgkmcnt(0)" ::: "memory")
#define SCHEDB() __builtin_amdgcn_sched_barrier(0)
#define BAR()    __builtin_amdgcn_s_barrier()

// Kernel 1: dotsQ[l][e] = int8 round((attr[e]·ev[l]) / 0.375), planes of 64 KB.
__global__ __launch_bounds__(256) void dots_kernel(
    const float* __restrict__ edge_attr,
    const float* __restrict__ edge_vector,
    signed char* __restrict__ dotsQ) {
  const int lane = threadIdx.x & 63;
  const int wib  = threadIdx.x >> 6;
  const int dg   = lane & 15;
  const int es   = lane >> 4;
  const int e    = blockIdx.x * 16 + wib * 4 + es;

  const float4 a = *(const float4*)(edge_attr + e * EDIM + dg * 4);
  float d[LL];
#pragma unroll
  for (int l = 0; l < LL; ++l) {
    const float4 ev = *(const float4*)(edge_vector + l * EDIM + dg * 4);
    d[l] = a.x * ev.x + a.y * ev.y + a.z * ev.z + a.w * ev.w;
  }
#pragma unroll
  for (int s = 1; s <= 8; s <<= 1) {
#pragma unroll
    for (int l = 0; l < LL; ++l) d[l] += __shfl_xor(d[l], s, 64);
  }
  if (dg < LL) {
    const float dv = (dg == 0) ? d[0] : (dg == 1) ? d[1] : (dg == 2) ? d[2]
                   : (dg == 3) ? d[3] : d[4];
    const float qf = fminf(fmaxf(dv * QINV, -127.f), 127.f);
    dotsQ[dg * EE + e] = (signed char)__float2int_rn(qf);
  }
}

__device__ __forceinline__ void stage_plane(const signed char* __restrict__ dotsQ,
                                            int plane, signed char* lbuf, int ltid) {
#pragma unroll
  for (int r = 0; r < 4; ++r) {              // 1024 thr x 4 x 16 B = 64 KB
    const int c = (r * 1024 + ltid) * 16;
    __builtin_amdgcn_global_load_lds(
        (const __attribute__((address_space(1))) void*)(dotsQ + (size_t)plane * EE + c),
        (__attribute__((address_space(3))) void*)(lbuf + c), 16, 0, 0);
  }
}

// Kernel 2: double-buffered pipelined gather (the R18 probes showed the three
// phases each ~10 us and the single-buffer kernel = their serial sum).
// Per pass l: gather plane l from buf[l&1]; lgkmcnt+barrier; issue stage of
// plane l+2 into buf[l&1]; counted vmcnt(8) guarantees plane l+1 landed while
// plane l+2 stays in flight under the next gather pass. 512 WGs halve the
// staged volume vs R14 (335 -> 167 MB). Live state ~45 regs < the 64-VGPR
// cap for 1024-thread WGs (spill detector: WRITE_SIZE).
__global__ __launch_bounds__(1024) void pairs_kernel(
    const int* __restrict__ ept,
    const signed char* __restrict__ dotsQ,
    float* __restrict__ out) {
  __shared__ __align__(16) signed char tab[2][EE];   // 128 KB
  const int ltid = threadIdx.x;
  const int tid  = blockIdx.x * 1024 + ltid;         // 0..TG-1

  // ---- prologue: idx loads FIRST (oldest in vmcnt order), then staging ----
  int4 v[2][5];
#pragma unroll
  for (int g = 0; g < 2; ++g) {
    const int4* p = (const int4*)(ept + ((size_t)g * TG + (size_t)tid) * 20);
#pragma unroll
    for (int q = 0; q < 5; ++q) v[g][q] = p[q];
  }
  SCHEDB();
  stage_plane(dotsQ, 0, tab[0], ltid);
  SCHEDB();
  stage_plane(dotsQ, 1, tab[1], ltid);
  SCHEDB();

  // pack (consumes idx -> compiler waits vmcnt(16): staging stays in flight)
  unsigned pk[20];
  unsigned cp = 0u;
#pragma unroll
  for (int g = 0; g < 2; ++g) {
#pragma unroll
    for (int q = 0; q < 5; ++q) {
#pragma unroll
      for (int jj = 0; jj < 4; ++jj) {
        const int sl = q * 4 + jj;
        const int k  = g * 4 + sl / 5;
        const int id = (jj == 0) ? v[g][q].x : (jj == 1) ? v[g][q].y
                     : (jj == 2) ? v[g][q].z : v[g][q].w;
        cp += ((id >= 0) ? 1u : 0u) << (k * 4);
        const unsigned e16 = (id < 0) ? 0u : (unsigned)id;
        const int sg = g * 20 + sl;
        if ((sg & 1) == 0) pk[sg >> 1] = e16;
        else               pk[sg >> 1] |= (e16 << 16);
      }
    }
  }
  asm volatile("" : "+v"(pk[0]), "+v"(pk[1]), "+v"(pk[2]), "+v"(pk[3]),
                    "+v"(pk[4]), "+v"(pk[5]), "+v"(pk[6]), "+v"(pk[7]),
                    "+v"(pk[8]), "+v"(pk[9]), "+v"(pk[10]), "+v"(pk[11]),
                    "+v"(pk[12]), "+v"(pk[13]), "+v"(pk[14]), "+v"(pk[15]),
                    "+v"(pk[16]), "+v"(pk[17]), "+v"(pk[18]), "+v"(pk[19]),
                    "+v"(cp));

  WAITV(8); SCHEDB(); BAR();                 // plane 0 landed; plane 1 in flight

  int sum[8];
#pragma unroll
  for (int k = 0; k < 8; ++k) sum[k] = 0;
  int t0v[LL];

#pragma unroll
  for (int l = 0; l < LL; ++l) {
    const signed char* tb = tab[l & 1];
    t0v[l] = (int)tb[0];                     // broadcast (correction)
#pragma unroll
    for (int k = 0; k < 8; ++k) {
      const int sg = k * LL + l;             // compile-time
      const unsigned r = pk[sg >> 1];
      const unsigned id = (sg & 1) ? (r >> 16) : (r & 0xffffu);
      sum[k] += (int)tb[id];
    }
    WAITL(); SCHEDB();
    BAR();                                   // all waves done reading buf[l&1]
    if (l + 2 <= 4) { stage_plane(dotsQ, l + 2, tab[l & 1], ltid); SCHEDB(); }
    if (l < 4) {
      if (l < 3) { WAITV(8); }               // plane l+1 landed, l+2 in flight
      else       { WAITV(0); }               // l=3: drain plane 4 (nothing newer)
      SCHEDB(); BAR();
    }
  }

  // ---- suffix sums of tab0 per plane: S[m] = sum_{l>=m} t0v[l] ----
  const int S4 = t0v[4];
  const int S3 = S4 + t0v[3];
  const int S2 = S3 + t0v[2];
  const int S1 = S2 + t0v[1];
  const int S0 = S1 + t0v[0];

#pragma unroll
  for (int g = 0; g < 2; ++g) {
    const size_t gid = (size_t)g * TG + (size_t)tid;
    float rr[4];
#pragma unroll
    for (int j = 0; j < 4; ++j) {
      const int k = g * 4 + j;
      const unsigned cnt = (cp >> (k * 4)) & 15u;
      const int corr = (cnt == 5) ? 0
                     : (cnt == 4) ? S4
                     : (cnt == 3) ? S3
                     : (cnt == 2) ? S2
                     : (cnt == 1) ? S1 : S0;
      rr[j] = (QS * (float)(sum[k] - corr)) / ((float)cnt + 1e-10f);  // cnt==0 -> 0
    }
    ((float4*)out)[gid] = make_float4(rr[0], rr[1], rr[2], rr[3]);
  }
}

extern "C" void kernel_launch(void* const* d_in, const int* in_sizes, int n_in,
                              void* d_out, int out_size, void* d_ws, size_t ws_size,
                              hipStream_t stream) {
  // d_in order: x(unused), edge_attr, edge_vector, edge_paths_tensor, edge_paths_length(unused)
  const float* edge_attr   = (const float*)d_in[1];
  const float* edge_vector = (const float*)d_in[2];
  const int*   ept         = (const int*)d_in[3];
  float* out = (float*)d_out;
  signed char* dotsQ = (signed char*)d_ws;   // L x E int8 = 320 KB scratch

  dots_kernel<<<EE / 16, 256, 0, stream>>>(edge_attr, edge_vector, dotsQ);

  // 512 WGs x 1024 threads, 8 pairs/thread; 128 KB LDS (2-plane dbuf).
  pairs_kernel<<<512, 1024, 0, stream>>>(ept, dotsQ, out);
}